// Round 9
// baseline (512.354 us; speedup 1.0000x reference)
//
#include <hip/hip_runtime.h>
#include <math.h>

#define NB 64
#define NN 100
#define HH 128
#define HC 16
#define NCH 8
#define NBLK 512

static constexpr float EPSBN = 1e-5f;

struct P {
    const float *X, *timev, *Wt1, *bt1, *Wt2, *bt2, *Wtn, *btn, *g_tn, *b_tn;
    const float *Wg1, *bg1, *g1, *bb1, *Wg2, *bg2, *g2, *bb2, *Wg3, *bg3, *g3, *bb3;
    const float *We0, *be0, *g_e0, *b_e0, *We1, *be1, *g_e1, *b_e1;
    float *Ah, *rs, *u1, *Dfull, *vi, *vj, *x1, *x2, *psi, *psj, *out;
    int *bcnt, *bgen;
};

// ---- software grid barrier: sense-reversing, device-scope (cross-XCD safe) ----
// Safe because grid (512) <= min co-residency capacity (3 blocks/CU x 256 CU = 768):
// work-conserving dispatch makes all blocks resident, so spinning cannot deadlock.
__device__ __forceinline__ void gridbar(int* cnt, int* gen) {
    __syncthreads();
    if (threadIdx.x == 0) {
        __threadfence();  // release: push writes to device-visible point
        int g = __hip_atomic_load(gen, __ATOMIC_RELAXED, __HIP_MEMORY_SCOPE_AGENT);
        int arrived = __hip_atomic_fetch_add(cnt, 1, __ATOMIC_ACQ_REL,
                                             __HIP_MEMORY_SCOPE_AGENT);
        if (arrived == NBLK - 1) {
            __hip_atomic_store(cnt, 0, __ATOMIC_RELAXED, __HIP_MEMORY_SCOPE_AGENT);
            __hip_atomic_fetch_add(gen, 1, __ATOMIC_ACQ_REL, __HIP_MEMORY_SCOPE_AGENT);
        } else {
            while (__hip_atomic_load(gen, __ATOMIC_ACQUIRE,
                                     __HIP_MEMORY_SCOPE_AGENT) == g) {
                __builtin_amdgcn_s_sleep(4);
            }
        }
        __threadfence();  // acquire: invalidate caches before reading others' data
    }
    __syncthreads();
}

// ---- one GCN layer (r7-verified): jp = t&3 (reduction split), ig = t>>2 ----
__device__ __forceinline__ void gcn_layer(
    const float* __restrict__ Ab, const float* __restrict__ xb,
    const float* __restrict__ W, const float* __restrict__ Wg1,
    const float* __restrict__ u1b, const float* __restrict__ rsb,
    const float* __restrict__ bg, const float* __restrict__ g,
    const float* __restrict__ bb, const float* __restrict__ vi,
    const float* __restrict__ vj, float* __restrict__ outb,
    float* __restrict__ psi, float* __restrict__ psj,
    float* sW, float* sZ, int hc, int hcb, int b, bool last, int t) {
    const int jp = t & 3, ig = t >> 2;
    const int r0 = ig, r1 = (ig < 36) ? 64 + ig : ig;
    float a0[16], a1[16];

    if (W == nullptr) {
        for (int idx = t; idx < 400; idx += 256) {
            int j = idx >> 2, c4 = idx & 3;
            *(float4*)&sZ[j * 20 + c4 * 4] = *(const float4*)&Wg1[j * HH + hc + c4 * 4];
        }
        for (int idx = t; idx < 240; idx += 256) sZ[2000 + idx] = 0.f;
        __syncthreads();
    } else {
        for (int idx = t; idx < 512; idx += 256) {
            int k = idx >> 2, c4 = idx & 3;
            int kp = ((k & 31) << 2) | (k >> 5);
            *(float4*)&sW[kp * 16 + c4 * 4] = *(const float4*)&W[k * HH + hc + c4 * 4];
        }
        for (int idx = t; idx < 240; idx += 256) sZ[2000 + idx] = 0.f;
        __syncthreads();
#pragma unroll
        for (int c = 0; c < 16; ++c) { a0[c] = 0.f; a1[c] = 0.f; }
        const int wb = jp << 4;
#pragma unroll
        for (int s = 0; s < 8; ++s) {
            const int k = (jp << 5) + s * 4;
            float4 x0 = *(const float4*)&xb[r0 * HH + k];
            float4 x1 = *(const float4*)&xb[r1 * HH + k];
#pragma unroll
            for (int kk = 0; kk < 4; ++kk) {
                const float e0 = (&x0.x)[kk], e1 = (&x1.x)[kk];
                const int wr = ((s * 4 + kk) << 6) + wb;
#pragma unroll
                for (int c4 = 0; c4 < 4; ++c4) {
                    float4 w = *(const float4*)&sW[wr + c4 * 4];
                    a0[c4 * 4 + 0] = fmaf(e0, w.x, a0[c4 * 4 + 0]);
                    a0[c4 * 4 + 1] = fmaf(e0, w.y, a0[c4 * 4 + 1]);
                    a0[c4 * 4 + 2] = fmaf(e0, w.z, a0[c4 * 4 + 2]);
                    a0[c4 * 4 + 3] = fmaf(e0, w.w, a0[c4 * 4 + 3]);
                    a1[c4 * 4 + 0] = fmaf(e1, w.x, a1[c4 * 4 + 0]);
                    a1[c4 * 4 + 1] = fmaf(e1, w.y, a1[c4 * 4 + 1]);
                    a1[c4 * 4 + 2] = fmaf(e1, w.z, a1[c4 * 4 + 2]);
                    a1[c4 * 4 + 3] = fmaf(e1, w.w, a1[c4 * 4 + 3]);
                }
            }
        }
#pragma unroll
        for (int c = 0; c < 16; ++c) {
            a0[c] += __shfl_xor(a0[c], 1); a0[c] += __shfl_xor(a0[c], 2);
            a1[c] += __shfl_xor(a1[c], 1); a1[c] += __shfl_xor(a1[c], 2);
        }
        if (jp == 0) {
#pragma unroll
            for (int c4 = 0; c4 < 4; ++c4) {
                *(float4*)&sZ[r0 * 20 + c4 * 4] =
                    make_float4(a0[c4 * 4 + 0], a0[c4 * 4 + 1], a0[c4 * 4 + 2], a0[c4 * 4 + 3]);
                if (ig < 36)
                    *(float4*)&sZ[r1 * 20 + c4 * 4] =
                        make_float4(a1[c4 * 4 + 0], a1[c4 * 4 + 1], a1[c4 * 4 + 2], a1[c4 * 4 + 3]);
            }
        }
        __syncthreads();
    }

    // phase 2: out = Ah @ z, j-quarter per jp
#pragma unroll
    for (int c = 0; c < 16; ++c) { a0[c] = 0.f; a1[c] = 0.f; }
    const int j0 = jp * 28;
#pragma unroll
    for (int s = 0; s < 7; ++s) {
        const int j = j0 + s * 4;
        float4 v0 = *(const float4*)&Ab[r0 * NN + j];
        float4 v1 = *(const float4*)&Ab[r1 * NN + j];
#pragma unroll
        for (int jj = 0; jj < 4; ++jj) {
            const float e0 = (&v0.x)[jj], e1 = (&v1.x)[jj];
            const int zr = (j + jj) * 20;
#pragma unroll
            for (int c4 = 0; c4 < 4; ++c4) {
                float4 z = *(const float4*)&sZ[zr + c4 * 4];
                a0[c4 * 4 + 0] = fmaf(e0, z.x, a0[c4 * 4 + 0]);
                a0[c4 * 4 + 1] = fmaf(e0, z.y, a0[c4 * 4 + 1]);
                a0[c4 * 4 + 2] = fmaf(e0, z.z, a0[c4 * 4 + 2]);
                a0[c4 * 4 + 3] = fmaf(e0, z.w, a0[c4 * 4 + 3]);
                a1[c4 * 4 + 0] = fmaf(e1, z.x, a1[c4 * 4 + 0]);
                a1[c4 * 4 + 1] = fmaf(e1, z.y, a1[c4 * 4 + 1]);
                a1[c4 * 4 + 2] = fmaf(e1, z.z, a1[c4 * 4 + 2]);
                a1[c4 * 4 + 3] = fmaf(e1, z.w, a1[c4 * 4 + 3]);
            }
        }
    }
#pragma unroll
    for (int c = 0; c < 16; ++c) {
        a0[c] += __shfl_xor(a0[c], 1); a0[c] += __shfl_xor(a0[c], 2);
        a1[c] += __shfl_xor(a1[c], 1); a1[c] += __shfl_xor(a1[c], 2);
    }
    if (jp == 0) {
        const float rinv = 1.0f / sqrtf(1.f + EPSBN);
        float y0[16], y1[16];
        const float rs0 = (W == nullptr) ? rsb[r0] : 0.f;
        const float rs1 = (W == nullptr) ? rsb[r1] : 0.f;
#pragma unroll
        for (int c4 = 0; c4 < 4; ++c4) {
            float4 gv = *(const float4*)&g[hc + c4 * 4];
            float4 bbv = *(const float4*)&bb[hc + c4 * 4];
            float4 bgv = *(const float4*)&bg[hc + c4 * 4];
            float4 uv = (W == nullptr) ? *(const float4*)&u1b[hc + c4 * 4]
                                       : make_float4(0.f, 0.f, 0.f, 0.f);
#pragma unroll
            for (int cc = 0; cc < 4; ++cc) {
                const int c = c4 * 4 + cc;
                float p0 = a0[c] + (&bgv.x)[cc], p1 = a1[c] + (&bgv.x)[cc];
                if (W == nullptr) {
                    p0 += rs0 * (&uv.x)[cc];
                    p1 += rs1 * (&uv.x)[cc];
                }
                y0[c] = fmaxf(fmaf((&gv.x)[cc] * rinv, p0, (&bbv.x)[cc]), 0.f);
                y1[c] = fmaxf(fmaf((&gv.x)[cc] * rinv, p1, (&bbv.x)[cc]), 0.f);
            }
        }
        if (last) {
            float pi0 = 0.f, pj0 = 0.f, pi1 = 0.f, pj1 = 0.f;
#pragma unroll
            for (int c = 0; c < 16; ++c) {
                const float vic = vi[hc + c], vjc = vj[hc + c];
                pi0 = fmaf(y0[c], vic, pi0); pj0 = fmaf(y0[c], vjc, pj0);
                pi1 = fmaf(y1[c], vic, pi1); pj1 = fmaf(y1[c], vjc, pj1);
            }
            psi[(b * NN + r0) * NCH + hcb] = pi0;
            psj[(b * NN + r0) * NCH + hcb] = pj0;
            if (ig < 36) {
                psi[(b * NN + r1) * NCH + hcb] = pi1;
                psj[(b * NN + r1) * NCH + hcb] = pj1;
            }
        } else {
#pragma unroll
            for (int c4 = 0; c4 < 4; ++c4) {
                *(float4*)&outb[r0 * HH + hc + c4 * 4] =
                    make_float4(y0[c4 * 4 + 0], y0[c4 * 4 + 1], y0[c4 * 4 + 2], y0[c4 * 4 + 3]);
                if (ig < 36)
                    *(float4*)&outb[r1 * HH + hc + c4 * 4] =
                        make_float4(y1[c4 * 4 + 0], y1[c4 * 4 + 1], y1[c4 * 4 + 2], y1[c4 * 4 + 3]);
            }
        }
    }
}

// grid 512 x 256; LDS 40.5KB + bounds(256,3) -> 3 blocks/CU -> capacity 768 >= 512.
__global__ __launch_bounds__(256, 3) void mega(P p) {
    __shared__ float sBuf[10000];
    __shared__ float sdinv[128];
    const int bx = blockIdx.x, t = threadIdx.x;
    const float rinv = 1.0f / sqrtf(1.f + EPSBN);
    const int b = bx & 63;     // XCD: bx%8 == b%8 in every phase
    const int hcb = bx >> 6;

    // =================== Phase A: setup ===================
    if (bx < 4 * NB) {
        const int s = hcb;  // 0..3: rows [25s, 25s+25)
        const float* Xb = p.X + b * NN * NN;
        float4* s4 = (float4*)sBuf;
        const float4* X4 = (const float4*)Xb;
        for (int idx = t; idx < NN * NN / 4; idx += 256) s4[idx] = X4[idx];
        __syncthreads();
        if (t < 200) {
            const int row = t >> 1, h = t & 1;
            const float4* r4 = (const float4*)(sBuf + row * NN);
            float d = 0.f;
            const int qs = h ? 13 : 0, qe = h ? 25 : 13;
            for (int q = qs; q < qe; ++q) {
                float4 v = r4[q];
                d += (v.x != 0.f ? 1.f : 0.f) + (v.y != 0.f ? 1.f : 0.f) +
                     (v.z != 0.f ? 1.f : 0.f) + (v.w != 0.f ? 1.f : 0.f);
            }
            d += __shfl_xor(d, 1);
            if (h == 0) {
                if (sBuf[row * NN + row] == 0.f) d += 1.f;
                sdinv[row] = 1.0f / sqrtf(d);
            }
        }
        __syncthreads();
        float* Ab = p.Ah + b * NN * NN;
        const int i0 = s * 25;
        for (int idx = t; idx < 25 * NN; idx += 256) {
            int il = idx / NN, j = idx - il * NN;
            int i = i0 + il;
            float at = (i == j) ? 1.f : (sBuf[i * NN + j] != 0.f ? 1.f : 0.f);
            Ab[i * NN + j] = sdinv[i] * at * sdinv[j];
        }
        if (t < 200) {
            const int rl = t >> 3, part = t & 7;
            const int i = i0 + rl;
            float ssum = 0.f;
            for (int j = part; j < NN; j += 8) {
                float at = (i == j) ? 1.f : (sBuf[i * NN + j] != 0.f ? 1.f : 0.f);
                ssum += at * sdinv[j];
            }
            ssum += __shfl_xor(ssum, 1, 8);
            ssum += __shfl_xor(ssum, 2, 8);
            ssum += __shfl_xor(ssum, 4, 8);
            if (part == 0) p.rs[b * NN + i] = sdinv[i] * ssum;
        }
    } else if (bx < 4 * NB + NB) {
        const int bm = bx - 4 * NB;  // (256+bm)%8 == bm%8
        float* s_temb = sBuf;
        float* s_h1 = sBuf + 128;
        float* s_h = sBuf + 256;
        float* s_tn = sBuf + 384;
        const float tt = p.timev[bm];
        if (t < 128) {
            int k = t & 63;
            float f = expf((float)k * (-logf(10000.f) / 63.f));
            float a = tt * f;
            s_temb[t] = (t < 64) ? sinf(a) : cosf(a);
        }
        __syncthreads();
        if (t < 128) {
            float acc = p.bt1[t];
            for (int q = 0; q < HH; ++q) acc = fmaf(s_temb[q], p.Wt1[q * HH + t], acc);
            s_h1[t] = fmaxf(acc, 0.f);
        }
        __syncthreads();
        if (t < 128) {
            float acc = p.bt2[t];
            for (int q = 0; q < HH; ++q) acc = fmaf(s_h1[q], p.Wt2[q * HH + t], acc);
            s_h[t] = acc;
        }
        __syncthreads();
        if (t < NN) {
            float v = p.btn[t];
            for (int q = 0; q < HH; ++q) v = fmaf(s_h[q], p.Wtn[q * NN + t], v);
            s_tn[t] = fmaxf(fmaf(p.g_tn[t] * rinv, v, p.b_tn[t]), 0.f);
        }
        __syncthreads();
        if (t < 128) {
            float acc = 0.f;
            for (int n = 0; n < NN; ++n) acc = fmaf(s_tn[n], p.Wg1[(NN + n) * HH + t], acc);
            p.u1[bm * HH + t] = acc;
        }
        if (t == 0) {
            float tp = 0.f;
            for (int q = 0; q < HH; ++q) tp = fmaf(s_h[q], p.We1[HH + q], tp);
            float K = 0.f;
            for (int hh = 0; hh < HH; ++hh)
                K += (p.be0[hh] * p.g_e0[hh] * rinv + p.b_e0[hh]) * p.We1[hh];
            p.Dfull[bm] = tp + K + p.be1[0];
        }
    } else if (bx == 4 * NB + NB) {
        if (t < 128) sBuf[t] = p.g_e0[t] * p.We1[t] * rinv;
        __syncthreads();
        if (t < 128) {
            float a = 0.f, cc = 0.f;
            for (int hh = 0; hh < HH; ++hh) {
                a = fmaf(p.We0[t * HH + hh], sBuf[hh], a);
                cc = fmaf(p.We0[(HH + t) * HH + hh], sBuf[hh], cc);
            }
            p.vi[t] = a;
            p.vj[t] = cc;
        }
    }
    gridbar(p.bcnt, p.bgen);

    // =================== Phases B/C/D: three GCN layers ===================
    float* sW = sBuf;
    float* sZ = sBuf + 2048;
    const float* Ab = p.Ah + b * NN * NN;
    const int hc = hcb * HC;

    gcn_layer(Ab, nullptr, nullptr, p.Wg1, p.u1 + b * HH, p.rs + b * NN,
              p.bg1, p.g1, p.bb1, nullptr, nullptr,
              p.x1 + b * NN * HH, nullptr, nullptr, sW, sZ, hc, hcb, b, false, t);
    gridbar(p.bcnt, p.bgen);

    gcn_layer(Ab, p.x1 + b * NN * HH, p.Wg2, nullptr, nullptr, nullptr,
              p.bg2, p.g2, p.bb2, nullptr, nullptr,
              p.x2 + b * NN * HH, nullptr, nullptr, sW, sZ, hc, hcb, b, false, t);
    gridbar(p.bcnt, p.bgen);

    gcn_layer(Ab, p.x2 + b * NN * HH, p.Wg3, nullptr, nullptr, nullptr,
              p.bg3, p.g3, p.bb3, p.vi, p.vj,
              nullptr, p.psi, p.psj, sW, sZ, hc, hcb, b, true, t);
    gridbar(p.bcnt, p.bgen);

    // =================== Phase E: out[b,i,j] = (i!=j)*bn(si+sj+D) ===================
    {
        const int i0 = hcb * 13;
        const int nr = (i0 + 13 <= NN) ? 13 : (NN - i0);  // seg 7 -> 9 rows
        float* ssj = sBuf;
        float* ssi = sBuf + 128;
        if (t < NN) {
            const float4* q4 = (const float4*)(p.psj + (b * NN + t) * NCH);
            float4 v0 = q4[0], v1 = q4[1];
            ssj[t] = v0.x + v0.y + v0.z + v0.w + v1.x + v1.y + v1.z + v1.w;
        }
        if (t >= 128 && t < 128 + nr) {
            int i = t - 128;
            const float4* q4 = (const float4*)(p.psi + (b * NN + i0 + i) * NCH);
            float4 v0 = q4[0], v1 = q4[1];
            ssi[i] = v0.x + v0.y + v0.z + v0.w + v1.x + v1.y + v1.z + v1.w;
        }
        __syncthreads();
        const float D = p.Dfull[b], ge = p.g_e1[0] * rinv, be = p.b_e1[0];
        float* ob = p.out + b * NN * NN + i0 * NN;
        for (int e = t; e < nr * NN; e += 256) {
            int ii = e / NN, j = e - ii * NN;
            float v = fmaf(ge, ssi[ii] + ssj[j] + D, be);
            ob[e] = (i0 + ii == j) ? 0.f : v;
        }
    }
}

extern "C" void kernel_launch(void* const* d_in, const int* in_sizes, int n_in,
                              void* d_out, int out_size, void* d_ws, size_t ws_size,
                              hipStream_t stream) {
    float* ws = (float*)d_ws;
    P p;
    p.X    = (const float*)d_in[0];
    p.timev= (const float*)d_in[1];
    p.Wt1  = (const float*)d_in[2];
    p.bt1  = (const float*)d_in[3];
    p.Wt2  = (const float*)d_in[4];
    p.bt2  = (const float*)d_in[5];
    p.Wtn  = (const float*)d_in[6];
    p.btn  = (const float*)d_in[7];
    p.g_tn = (const float*)d_in[8];
    p.b_tn = (const float*)d_in[9];
    p.Wg1  = (const float*)d_in[10];
    p.bg1  = (const float*)d_in[11];
    p.g1   = (const float*)d_in[12];
    p.bb1  = (const float*)d_in[13];
    p.Wg2  = (const float*)d_in[14];
    p.bg2  = (const float*)d_in[15];
    p.g2   = (const float*)d_in[16];
    p.bb2  = (const float*)d_in[17];
    p.Wg3  = (const float*)d_in[18];
    p.bg3  = (const float*)d_in[19];
    p.g3   = (const float*)d_in[20];
    p.bb3  = (const float*)d_in[21];
    p.We0  = (const float*)d_in[22];
    p.be0  = (const float*)d_in[23];
    p.g_e0 = (const float*)d_in[24];
    p.b_e0 = (const float*)d_in[25];
    p.We1  = (const float*)d_in[26];
    p.be1  = (const float*)d_in[27];
    p.g_e1 = (const float*)d_in[28];
    p.b_e1 = (const float*)d_in[29];

    // barrier cells in their own 256B region at ws start
    p.bcnt  = (int*)ws;           // ws[0]
    p.bgen  = (int*)ws + 16;      // ws[16] (separate cacheline)
    float* base = ws + 64;
    p.Ah    = base;               // 640000
    p.rs    = p.Ah + 640000;      // 6400
    p.u1    = p.rs + 6400;        // 8192
    p.Dfull = p.u1 + 8192;        // 64
    p.vi    = p.Dfull + 64;       // 128
    p.vj    = p.vi + 128;         // 128
    float* x1 = p.vj + 128;       // 819200 (dead after layer2; psi/psj alias)
    p.x1    = x1;
    p.x2    = x1 + 819200;        // 819200
    p.psi   = x1;                 // 51200
    p.psj   = x1 + 51200;         // 51200
    p.out   = (float*)d_out;

    hipMemsetAsync(ws, 0, 256, stream);  // zero barrier state every call
    mega<<<dim3(NBLK), dim3(256), 0, stream>>>(p);
}

// Round 10
// 64.064 us; speedup vs baseline: 7.9976x; 7.9976x over previous
//
#include <hip/hip_runtime.h>
#include <math.h>

#define NB 64
#define NN 100
#define HH 128
#define HC 8
#define NCH 16

static constexpr float EPSBN = 1e-5f;

// ============ fused setup: adjacency (blocks 0-255), time MLP (256-319), vij (320) ====
// XCD-aligned decode: adjacency b = bx & 63 (bid%8 == b%8 matches layer kernels).
__global__ __launch_bounds__(256) void k_setup(
    const float* __restrict__ X, const float* __restrict__ timev,
    const float* __restrict__ Wt1, const float* __restrict__ bt1,
    const float* __restrict__ Wt2, const float* __restrict__ bt2,
    const float* __restrict__ Wtn, const float* __restrict__ btn,
    const float* __restrict__ g_tn, const float* __restrict__ b_tn,
    const float* __restrict__ Wg1, const float* __restrict__ We0,
    const float* __restrict__ We1, const float* __restrict__ be1,
    const float* __restrict__ be0, const float* __restrict__ g_e0,
    const float* __restrict__ b_e0,
    float* __restrict__ Ah, float* __restrict__ rs,
    float* __restrict__ u1, float* __restrict__ Dfull,
    float* __restrict__ vi, float* __restrict__ vj) {
    __shared__ float sBuf[NN * NN];
    __shared__ float sdinv[128];
    const int bx = blockIdx.x, t = threadIdx.x;
    const float rinv = 1.0f / sqrtf(1.f + EPSBN);

    if (bx < 4 * NB) {
        const int b = bx & 63, s = bx >> 6;   // XCD-aligned: bx%8 == b%8
        const float* Xb = X + b * NN * NN;
        float4* s4 = (float4*)sBuf;
        const float4* X4 = (const float4*)Xb;
        for (int idx = t; idx < NN * NN / 4; idx += 256) s4[idx] = X4[idx];
        __syncthreads();
        if (t < 200) {
            const int row = t >> 1, h = t & 1;
            const float4* r4 = (const float4*)(sBuf + row * NN);
            float d = 0.f;
            const int qs = h ? 13 : 0, qe = h ? 25 : 13;
            for (int q = qs; q < qe; ++q) {
                float4 v = r4[q];
                d += (v.x != 0.f ? 1.f : 0.f) + (v.y != 0.f ? 1.f : 0.f) +
                     (v.z != 0.f ? 1.f : 0.f) + (v.w != 0.f ? 1.f : 0.f);
            }
            d += __shfl_xor(d, 1);
            if (h == 0) {
                if (sBuf[row * NN + row] == 0.f) d += 1.f;
                sdinv[row] = 1.0f / sqrtf(d);
            }
        }
        __syncthreads();
        float* Ab = Ah + b * NN * NN;
        const int i0 = s * 25;
        for (int idx = t; idx < 25 * NN; idx += 256) {
            int il = idx / NN, j = idx - il * NN;
            int i = i0 + il;
            float at = (i == j) ? 1.f : (sBuf[i * NN + j] != 0.f ? 1.f : 0.f);
            Ab[i * NN + j] = sdinv[i] * at * sdinv[j];
        }
        if (t < 200) {
            const int rl = t >> 3, part = t & 7;
            const int i = i0 + rl;
            float ssum = 0.f;
            for (int j = part; j < NN; j += 8) {
                float at = (i == j) ? 1.f : (sBuf[i * NN + j] != 0.f ? 1.f : 0.f);
                ssum += at * sdinv[j];
            }
            ssum += __shfl_xor(ssum, 1, 8);
            ssum += __shfl_xor(ssum, 2, 8);
            ssum += __shfl_xor(ssum, 4, 8);
            if (part == 0) rs[b * NN + i] = sdinv[i] * ssum;
        }
        return;
    }
    if (bx < 4 * NB + NB) {
        const int b = bx - 4 * NB;
        float* s_temb = sBuf;
        float* s_h1 = sBuf + 128;
        float* s_h = sBuf + 256;
        float* s_tn = sBuf + 384;
        const float tt = timev[b];
        if (t < 128) {
            int k = t & 63;
            float f = expf((float)k * (-logf(10000.f) / 63.f));
            float a = tt * f;
            s_temb[t] = (t < 64) ? sinf(a) : cosf(a);
        }
        __syncthreads();
        if (t < 128) {
            float acc = bt1[t];
            for (int q = 0; q < HH; ++q) acc = fmaf(s_temb[q], Wt1[q * HH + t], acc);
            s_h1[t] = fmaxf(acc, 0.f);
        }
        __syncthreads();
        if (t < 128) {
            float acc = bt2[t];
            for (int q = 0; q < HH; ++q) acc = fmaf(s_h1[q], Wt2[q * HH + t], acc);
            s_h[t] = acc;
        }
        __syncthreads();
        if (t < NN) {
            float v = btn[t];
            for (int q = 0; q < HH; ++q) v = fmaf(s_h[q], Wtn[q * NN + t], v);
            s_tn[t] = fmaxf(fmaf(g_tn[t] * rinv, v, b_tn[t]), 0.f);
        }
        __syncthreads();
        if (t < 128) {
            float acc = 0.f;
            for (int n = 0; n < NN; ++n) acc = fmaf(s_tn[n], Wg1[(NN + n) * HH + t], acc);
            u1[b * HH + t] = acc;
        }
        if (t == 0) {
            float tp = 0.f;
            for (int q = 0; q < HH; ++q) tp = fmaf(s_h[q], We1[HH + q], tp);
            float K = 0.f;
            for (int hh = 0; hh < HH; ++hh)
                K += (be0[hh] * g_e0[hh] * rinv + b_e0[hh]) * We1[hh];
            Dfull[b] = tp + K + be1[0];
        }
        return;
    }
    if (t < 128) sBuf[t] = g_e0[t] * We1[t] * rinv;
    __syncthreads();
    if (t < 128) {
        float a = 0.f, cc = 0.f;
        for (int hh = 0; hh < HH; ++hh) {
            a = fmaf(We0[t * HH + hh], sBuf[hh], a);
            cc = fmaf(We0[(HH + t) * HH + hh], sBuf[hh], cc);
        }
        vi[t] = a;
        vj[t] = cc;
    }
}

// ================= layer 1: out = relu(bn(Ah @ Wg1[:N,hc:hc+8] + rs*u1 + bg1)) ========
// grid (NB, 16); block 256 = (jp = t&3 j-quarter, ig = t>>2). 2 rows x 8 cols/thread.
__global__ __launch_bounds__(256, 4) void k_l1(
    const float* __restrict__ Ah, const float* __restrict__ Wg1,
    const float* __restrict__ u1, const float* __restrict__ rs,
    const float* __restrict__ bg1, const float* __restrict__ g1,
    const float* __restrict__ bb1, float* __restrict__ out) {
    __shared__ float sZ[112 * 12];  // [j][12-pad]; rows 100..111 zeroed
    const int b = blockIdx.x, hc = blockIdx.y * HC;
    const int t = threadIdx.x, jp = t & 3, ig = t >> 2;
    for (int idx = t; idx < 200; idx += 256) {
        int j = idx >> 1, c4 = idx & 1;
        *(float4*)&sZ[j * 12 + c4 * 4] = *(const float4*)&Wg1[j * HH + hc + c4 * 4];
    }
    for (int idx = t; idx < 144; idx += 256) sZ[1200 + idx] = 0.f;
    __syncthreads();
    const int r0 = ig, r1 = (ig < 36) ? 64 + ig : ig;
    float a0[8], a1[8];
#pragma unroll
    for (int c = 0; c < 8; ++c) { a0[c] = 0.f; a1[c] = 0.f; }
    const float* __restrict__ Ab = Ah + b * NN * NN;
    const int j0 = jp * 28;
#pragma unroll
    for (int s = 0; s < 7; ++s) {
        const int j = j0 + s * 4;
        float4 v0 = *(const float4*)&Ab[r0 * NN + j];
        float4 v1 = *(const float4*)&Ab[r1 * NN + j];
#pragma unroll
        for (int jj = 0; jj < 4; ++jj) {
            const float e0 = (&v0.x)[jj], e1 = (&v1.x)[jj];
            const int zr = (j + jj) * 12;
#pragma unroll
            for (int c4 = 0; c4 < 2; ++c4) {
                float4 z = *(const float4*)&sZ[zr + c4 * 4];
                a0[c4 * 4 + 0] = fmaf(e0, z.x, a0[c4 * 4 + 0]);
                a0[c4 * 4 + 1] = fmaf(e0, z.y, a0[c4 * 4 + 1]);
                a0[c4 * 4 + 2] = fmaf(e0, z.z, a0[c4 * 4 + 2]);
                a0[c4 * 4 + 3] = fmaf(e0, z.w, a0[c4 * 4 + 3]);
                a1[c4 * 4 + 0] = fmaf(e1, z.x, a1[c4 * 4 + 0]);
                a1[c4 * 4 + 1] = fmaf(e1, z.y, a1[c4 * 4 + 1]);
                a1[c4 * 4 + 2] = fmaf(e1, z.z, a1[c4 * 4 + 2]);
                a1[c4 * 4 + 3] = fmaf(e1, z.w, a1[c4 * 4 + 3]);
            }
        }
    }
#pragma unroll
    for (int c = 0; c < 8; ++c) {
        a0[c] += __shfl_xor(a0[c], 1); a0[c] += __shfl_xor(a0[c], 2);
        a1[c] += __shfl_xor(a1[c], 1); a1[c] += __shfl_xor(a1[c], 2);
    }
    if (jp == 0) {
        const float rinv = 1.0f / sqrtf(1.f + EPSBN);
        const float rs0 = rs[b * NN + r0], rs1 = rs[b * NN + r1];
        float* ob = out + b * NN * HH;
#pragma unroll
        for (int c4 = 0; c4 < 2; ++c4) {
            float4 gv = *(const float4*)&g1[hc + c4 * 4];
            float4 bbv = *(const float4*)&bb1[hc + c4 * 4];
            float4 bgv = *(const float4*)&bg1[hc + c4 * 4];
            float4 uv = *(const float4*)&u1[b * HH + hc + c4 * 4];
            float4 y0, y1;
#pragma unroll
            for (int cc = 0; cc < 4; ++cc) {
                const int c = c4 * 4 + cc;
                (&y0.x)[cc] = fmaxf(fmaf((&gv.x)[cc] * rinv,
                                         a0[c] + rs0 * (&uv.x)[cc] + (&bgv.x)[cc],
                                         (&bbv.x)[cc]), 0.f);
                (&y1.x)[cc] = fmaxf(fmaf((&gv.x)[cc] * rinv,
                                         a1[c] + rs1 * (&uv.x)[cc] + (&bgv.x)[cc],
                                         (&bbv.x)[cc]), 0.f);
            }
            *(float4*)&ob[r0 * HH + hc + c4 * 4] = y0;
            if (ig < 36) *(float4*)&ob[r1 * HH + hc + c4 * 4] = y1;
        }
    }
}

// ========= fused layer: z = x @ Wtile (k-split, shfl, ->LDS); out = Ah @ z (j-split) ====
template <bool LAST>
__global__ __launch_bounds__(256, 4) void k_layer(
    const float* __restrict__ Ah, const float* __restrict__ xin,
    const float* __restrict__ W, const float* __restrict__ bg,
    const float* __restrict__ g, const float* __restrict__ bb,
    const float* __restrict__ vi, const float* __restrict__ vj,
    float* __restrict__ out, float* __restrict__ psi, float* __restrict__ psj) {
    __shared__ float sW[128 * 8];   // [k'][8], k' = (k&31)*4 + (k>>5) (conflict-free)
    __shared__ float sZ[112 * 12];  // [j][12-pad]; rows 100..111 zeroed
    const int b = blockIdx.x, hcb = blockIdx.y, hc = hcb * HC;
    const int t = threadIdx.x, jp = t & 3, ig = t >> 2;
    {
        int k = t >> 1, c4 = t & 1;
        int kp = ((k & 31) << 2) | (k >> 5);
        *(float4*)&sW[kp * 8 + c4 * 4] = *(const float4*)&W[k * HH + hc + c4 * 4];
    }
    for (int idx = t; idx < 144; idx += 256) sZ[1200 + idx] = 0.f;
    __syncthreads();
    const int r0 = ig, r1 = (ig < 36) ? 64 + ig : ig;
    const float* __restrict__ xb = xin + b * NN * HH;
    float a0[8], a1[8];
#pragma unroll
    for (int c = 0; c < 8; ++c) { a0[c] = 0.f; a1[c] = 0.f; }
    // ---- phase 1: z = x @ Wtile, k in [jp*32, jp*32+32) ----
#pragma unroll
    for (int s = 0; s < 8; ++s) {
        const int k = (jp << 5) + s * 4;
        float4 x0 = *(const float4*)&xb[r0 * HH + k];
        float4 x1 = *(const float4*)&xb[r1 * HH + k];
#pragma unroll
        for (int kk = 0; kk < 4; ++kk) {
            const float e0 = (&x0.x)[kk], e1 = (&x1.x)[kk];
            const int wr = (((s * 4 + kk) << 2) | jp) * 8;
#pragma unroll
            for (int c4 = 0; c4 < 2; ++c4) {
                float4 w = *(const float4*)&sW[wr + c4 * 4];
                a0[c4 * 4 + 0] = fmaf(e0, w.x, a0[c4 * 4 + 0]);
                a0[c4 * 4 + 1] = fmaf(e0, w.y, a0[c4 * 4 + 1]);
                a0[c4 * 4 + 2] = fmaf(e0, w.z, a0[c4 * 4 + 2]);
                a0[c4 * 4 + 3] = fmaf(e0, w.w, a0[c4 * 4 + 3]);
                a1[c4 * 4 + 0] = fmaf(e1, w.x, a1[c4 * 4 + 0]);
                a1[c4 * 4 + 1] = fmaf(e1, w.y, a1[c4 * 4 + 1]);
                a1[c4 * 4 + 2] = fmaf(e1, w.z, a1[c4 * 4 + 2]);
                a1[c4 * 4 + 3] = fmaf(e1, w.w, a1[c4 * 4 + 3]);
            }
        }
    }
#pragma unroll
    for (int c = 0; c < 8; ++c) {
        a0[c] += __shfl_xor(a0[c], 1); a0[c] += __shfl_xor(a0[c], 2);
        a1[c] += __shfl_xor(a1[c], 1); a1[c] += __shfl_xor(a1[c], 2);
    }
    if (jp == 0) {
#pragma unroll
        for (int c4 = 0; c4 < 2; ++c4) {
            *(float4*)&sZ[r0 * 12 + c4 * 4] =
                make_float4(a0[c4 * 4 + 0], a0[c4 * 4 + 1], a0[c4 * 4 + 2], a0[c4 * 4 + 3]);
            if (ig < 36)
                *(float4*)&sZ[r1 * 12 + c4 * 4] =
                    make_float4(a1[c4 * 4 + 0], a1[c4 * 4 + 1], a1[c4 * 4 + 2], a1[c4 * 4 + 3]);
        }
    }
    __syncthreads();
    // ---- phase 2: out = Ah @ z, j-quarter per jp ----
#pragma unroll
    for (int c = 0; c < 8; ++c) { a0[c] = 0.f; a1[c] = 0.f; }
    const float* __restrict__ Ab = Ah + b * NN * NN;
    const int j0 = jp * 28;
#pragma unroll
    for (int s = 0; s < 7; ++s) {
        const int j = j0 + s * 4;
        float4 v0 = *(const float4*)&Ab[r0 * NN + j];
        float4 v1 = *(const float4*)&Ab[r1 * NN + j];
#pragma unroll
        for (int jj = 0; jj < 4; ++jj) {
            const float e0 = (&v0.x)[jj], e1 = (&v1.x)[jj];
            const int zr = (j + jj) * 12;
#pragma unroll
            for (int c4 = 0; c4 < 2; ++c4) {
                float4 z = *(const float4*)&sZ[zr + c4 * 4];
                a0[c4 * 4 + 0] = fmaf(e0, z.x, a0[c4 * 4 + 0]);
                a0[c4 * 4 + 1] = fmaf(e0, z.y, a0[c4 * 4 + 1]);
                a0[c4 * 4 + 2] = fmaf(e0, z.z, a0[c4 * 4 + 2]);
                a0[c4 * 4 + 3] = fmaf(e0, z.w, a0[c4 * 4 + 3]);
                a1[c4 * 4 + 0] = fmaf(e1, z.x, a1[c4 * 4 + 0]);
                a1[c4 * 4 + 1] = fmaf(e1, z.y, a1[c4 * 4 + 1]);
                a1[c4 * 4 + 2] = fmaf(e1, z.z, a1[c4 * 4 + 2]);
                a1[c4 * 4 + 3] = fmaf(e1, z.w, a1[c4 * 4 + 3]);
            }
        }
    }
#pragma unroll
    for (int c = 0; c < 8; ++c) {
        a0[c] += __shfl_xor(a0[c], 1); a0[c] += __shfl_xor(a0[c], 2);
        a1[c] += __shfl_xor(a1[c], 1); a1[c] += __shfl_xor(a1[c], 2);
    }
    if (jp == 0) {
        const float rinv = 1.0f / sqrtf(1.f + EPSBN);
        float y0[8], y1[8];
#pragma unroll
        for (int c4 = 0; c4 < 2; ++c4) {
            float4 gv = *(const float4*)&g[hc + c4 * 4];
            float4 bbv = *(const float4*)&bb[hc + c4 * 4];
            float4 bgv = *(const float4*)&bg[hc + c4 * 4];
#pragma unroll
            for (int cc = 0; cc < 4; ++cc) {
                const int c = c4 * 4 + cc;
                y0[c] = fmaxf(fmaf((&gv.x)[cc] * rinv, a0[c] + (&bgv.x)[cc], (&bbv.x)[cc]), 0.f);
                y1[c] = fmaxf(fmaf((&gv.x)[cc] * rinv, a1[c] + (&bgv.x)[cc], (&bbv.x)[cc]), 0.f);
            }
        }
        if (LAST) {
            float pi0 = 0.f, pj0 = 0.f, pi1 = 0.f, pj1 = 0.f;
#pragma unroll
            for (int c = 0; c < 8; ++c) {
                const float vic = vi[hc + c], vjc = vj[hc + c];
                pi0 = fmaf(y0[c], vic, pi0); pj0 = fmaf(y0[c], vjc, pj0);
                pi1 = fmaf(y1[c], vic, pi1); pj1 = fmaf(y1[c], vjc, pj1);
            }
            psi[(b * NN + r0) * NCH + hcb] = pi0;
            psj[(b * NN + r0) * NCH + hcb] = pj0;
            if (ig < 36) {
                psi[(b * NN + r1) * NCH + hcb] = pi1;
                psj[(b * NN + r1) * NCH + hcb] = pj1;
            }
        } else {
            float* ob = out + b * NN * HH;
#pragma unroll
            for (int c4 = 0; c4 < 2; ++c4) {
                *(float4*)&ob[r0 * HH + hc + c4 * 4] =
                    make_float4(y0[c4 * 4 + 0], y0[c4 * 4 + 1], y0[c4 * 4 + 2], y0[c4 * 4 + 3]);
                if (ig < 36)
                    *(float4*)&ob[r1 * HH + hc + c4 * 4] =
                        make_float4(y1[c4 * 4 + 0], y1[c4 * 4 + 1], y1[c4 * 4 + 2], y1[c4 * 4 + 3]);
            }
        }
    }
}

// ============ out[b,i,j] = (i!=j) * bn(si+sj+D) ============
__global__ __launch_bounds__(256) void k_out(
    const float* __restrict__ psi, const float* __restrict__ psj,
    const float* __restrict__ Dfull, const float* __restrict__ g_e1,
    const float* __restrict__ b_e1, float* __restrict__ outp) {
    __shared__ float ssi[25], ssj[NN];
    const int b = blockIdx.x, i0 = blockIdx.y * 25;
    const int t = threadIdx.x;
    if (t < NN) {
        float s = 0.f;
        const float4* p = (const float4*)(psj + (b * NN + t) * NCH);
#pragma unroll
        for (int q = 0; q < NCH / 4; ++q) {
            float4 v = p[q];
            s += v.x + v.y + v.z + v.w;
        }
        ssj[t] = s;
    }
    if (t >= 128 && t < 128 + 25) {
        int i = t - 128;
        float s = 0.f;
        const float4* p = (const float4*)(psi + (b * NN + i0 + i) * NCH);
#pragma unroll
        for (int q = 0; q < NCH / 4; ++q) {
            float4 v = p[q];
            s += v.x + v.y + v.z + v.w;
        }
        ssi[i] = s;
    }
    __syncthreads();
    const float rinv = 1.0f / sqrtf(1.f + EPSBN);
    const float D = Dfull[b], ge = g_e1[0] * rinv, be = b_e1[0];
    float* ob = outp + b * NN * NN + i0 * NN;
    for (int e = t; e < 25 * NN; e += 256) {
        int ii = e / NN, j = e - ii * NN;
        float v = fmaf(ge, ssi[ii] + ssj[j] + D, be);
        ob[e] = (i0 + ii == j) ? 0.f : v;
    }
}

extern "C" void kernel_launch(void* const* d_in, const int* in_sizes, int n_in,
                              void* d_out, int out_size, void* d_ws, size_t ws_size,
                              hipStream_t stream) {
    const float* X    = (const float*)d_in[0];
    const float* timev= (const float*)d_in[1];
    const float* Wt1  = (const float*)d_in[2];
    const float* bt1  = (const float*)d_in[3];
    const float* Wt2  = (const float*)d_in[4];
    const float* bt2  = (const float*)d_in[5];
    const float* Wtn  = (const float*)d_in[6];
    const float* btn  = (const float*)d_in[7];
    const float* g_tn = (const float*)d_in[8];
    const float* b_tn = (const float*)d_in[9];
    const float* Wg1  = (const float*)d_in[10];
    const float* bg1  = (const float*)d_in[11];
    const float* g1   = (const float*)d_in[12];
    const float* bb1  = (const float*)d_in[13];
    const float* Wg2  = (const float*)d_in[14];
    const float* bg2  = (const float*)d_in[15];
    const float* g2   = (const float*)d_in[16];
    const float* bb2  = (const float*)d_in[17];
    const float* Wg3  = (const float*)d_in[18];
    const float* bg3  = (const float*)d_in[19];
    const float* g3   = (const float*)d_in[20];
    const float* bb3  = (const float*)d_in[21];
    const float* We0  = (const float*)d_in[22];
    const float* be0  = (const float*)d_in[23];
    const float* g_e0 = (const float*)d_in[24];
    const float* b_e0 = (const float*)d_in[25];
    const float* We1  = (const float*)d_in[26];
    const float* be1  = (const float*)d_in[27];
    const float* g_e1 = (const float*)d_in[28];
    const float* b_e1 = (const float*)d_in[29];

    float* ws = (float*)d_ws;
    float* Ah    = ws;            // 640000
    float* rs    = Ah + 640000;   // 6400
    float* u1    = rs + 6400;     // 8192
    float* Dfull = u1 + 8192;     // 64
    float* vi    = Dfull + 64;    // 128
    float* vj    = vi + 128;      // 128
    float* x1    = vj + 128;      // 819200 (dead after layer2 -> psi/psj alias)
    float* x2    = x1 + 819200;   // 819200
    float* psi   = x1;            // 102400
    float* psj   = x1 + 102400;   // 102400

    k_setup<<<dim3(4 * NB + NB + 1), dim3(256), 0, stream>>>(
        X, timev, Wt1, bt1, Wt2, bt2, Wtn, btn, g_tn, b_tn, Wg1, We0, We1, be1,
        be0, g_e0, b_e0, Ah, rs, u1, Dfull, vi, vj);

    // XCD-aligned grids: batch is the fast blockIdx dim -> XCD = b%8 everywhere.
    k_l1<<<dim3(NB, NCH), dim3(256), 0, stream>>>(Ah, Wg1, u1, rs, bg1, g1, bb1, x1);
    k_layer<false><<<dim3(NB, NCH), dim3(256), 0, stream>>>(Ah, x1, Wg2, bg2, g2, bb2,
                                                            nullptr, nullptr, x2,
                                                            nullptr, nullptr);
    k_layer<true><<<dim3(NB, NCH), dim3(256), 0, stream>>>(Ah, x2, Wg3, bg3, g3, bb3,
                                                           vi, vj, nullptr, psi, psj);

    k_out<<<dim3(NB, 4), dim3(256), 0, stream>>>(psi, psj, Dfull, g_e1, b_e1,
                                                 (float*)d_out);
}